// Round 2
// baseline (376.267 us; speedup 1.0000x reference)
//
#include <hip/hip_runtime.h>

typedef __bf16 bf16x8 __attribute__((ext_vector_type(8)));
typedef float f32x4 __attribute__((ext_vector_type(4)));

__device__ __forceinline__ unsigned short f2b(float f) {
  unsigned u = __builtin_bit_cast(unsigned, f);
  u = (u + 0x7FFFu + ((u >> 16) & 1u)) >> 16;
  return (unsigned short)u;
}
__device__ __forceinline__ float b2f(unsigned short h) {
  return __builtin_bit_cast(float, (unsigned)h << 16);
}

// ---------------------------------------------------------------------------
// posenc writers (fp32 now): [x, sin(2^0 x)(C), cos(2^0 x)(C), ...]
// ---------------------------------------------------------------------------
__device__ __forceinline__ void posenc3(float* dst, float x, float y, float z, int F) {
  dst[0] = x; dst[1] = y; dst[2] = z;
  float fr = 1.0f;
  int o = 3;
  for (int f = 0; f < F; ++f) {
    float s, c;
    sincosf(x * fr, &s, &c); dst[o + 0] = s; dst[o + 3] = c;
    sincosf(y * fr, &s, &c); dst[o + 1] = s; dst[o + 4] = c;
    sincosf(z * fr, &s, &c); dst[o + 2] = s; dst[o + 5] = c;
    o += 6; fr *= 2.0f;
  }
}

__device__ __forceinline__ void posenc1(float* dst, float x, int F) {
  dst[0] = x;
  float fr = 1.0f;
  int o = 1;
  for (int f = 0; f < F; ++f) {
    float s, c;
    sincosf(x * fr, &s, &c);
    dst[o] = s; dst[o + 1] = c;
    o += 2; fr *= 2.0f;
  }
}

// ---------------------------------------------------------------------------
// Kernel 1: weight prep fp32 -> split bf16 planes (hi + lo).
// W0 [256,511] reordered/padded to [256,512]: col 255 = 0, cols 256..511 =
// orig 255..510 (the fvec block), matching the X layout below.
// ---------------------------------------------------------------------------
__global__ __launch_bounds__(256) void prep_weights(
    const float* __restrict__ W0, const float* __restrict__ W1,
    const float* __restrict__ W2,
    unsigned short* __restrict__ w0h, unsigned short* __restrict__ w0l,
    unsigned short* __restrict__ w1h, unsigned short* __restrict__ w1l,
    unsigned short* __restrict__ w2h, unsigned short* __restrict__ w2l)
{
  int i = blockIdx.x * 256 + threadIdx.x;   // 0 .. 262143
  float v;
  unsigned short* ph;
  unsigned short* pl;
  int j;
  if (i < 131072) {
    int n = i >> 9, c = i & 511;
    v = (c < 255) ? W0[n * 511 + c] : ((c == 255) ? 0.0f : W0[n * 511 + (c - 1)]);
    ph = w0h; pl = w0l; j = i;
  } else if (i < 196608) {
    j = i - 131072; v = W1[j]; ph = w1h; pl = w1l;
  } else {
    j = i - 196608; v = W2[j]; ph = w2h; pl = w2l;
  }
  unsigned short h = f2b(v);
  ph[j] = h;
  pl[j] = f2b(v - b2f(h));
}

// ---------------------------------------------------------------------------
// Kernel 2: ball query + feature assembly -> X [24576, 256] fp32
// (cols 0..254 computed features, col 255 = 0; fvec block is read directly
//  by the GEMM from the original input).
// 2 threads per query: role A = particles [0,2048), role B = [2048,4096).
// B stores its first-16 hits in LDS; A merges in index order.
// ---------------------------------------------------------------------------
__global__ __launch_bounds__(128) void feat_kernel(
    const float* __restrict__ points,   // [24576,3]
    const float* __restrict__ normals,  // [24576,3]
    const float* __restrict__ parts,    // [4096,3]
    const float* __restrict__ rays,     // [512,6]
    const float* __restrict__ ro,       // [3]
    float* __restrict__ X)              // [24576,256] fp32
{
  __shared__ float psx[4096], psy[4096], psz[4096];
  __shared__ float bpos[64][51];   // 51 stride breaks bank alignment
  __shared__ int   bcnt[64];

  const int tid = threadIdx.x;
  for (int j = tid; j < 4096; j += 128) {
    psx[j] = parts[3 * j + 0];
    psy[j] = parts[3 * j + 1];
    psz[j] = parts[3 * j + 2];
  }
  __syncthreads();

  const int role = tid >> 6;          // wave 0 = A, wave 1 = B
  const int ql   = tid & 63;
  const int q    = blockIdx.x * 64 + ql;
  const float qx = points[3 * q], qy = points[3 * q + 1], qz = points[3 * q + 2];
  const float RQ = 0.1f * 0.1f;       // fp32, matches reference radius*radius

  int n = 0;
  float sdx = 0, sdy = 0, sdz = 0;          // sum of (p - q) over accepted
  float s2x = 0, s2y = 0, s2z = 0;          // sum of (p - q)^2
  float sw = 0, swx = 0, swy = 0, swz = 0;  // sum w, sum w*p

  if (role == 0) {
    #pragma unroll 4
    for (int j = 0; j < 2048; ++j) {
      float px = psx[j], py = psy[j], pz = psz[j];
      float ex = px - qx, ey = py - qy, ez = pz - qz;
      float d2 = __fadd_rn(__fadd_rn(__fmul_rn(ex, ex), __fmul_rn(ey, ey)), __fmul_rn(ez, ez));
      if (d2 < RQ && n < 16) {
        n++;
        sdx += ex; sdy += ey; sdz += ez;
        s2x += ex * ex; s2y += ey * ey; s2z += ez * ez;
        float dn = sqrtf(d2);
        float t = dn * 10.0f;
        float w = fmaxf(1.0f - t * t * t, 0.0f);
        sw += w; swx += w * px; swy += w * py; swz += w * pz;
      }
    }
  } else {
    #pragma unroll 4
    for (int j = 2048; j < 4096; ++j) {
      float px = psx[j], py = psy[j], pz = psz[j];
      float ex = px - qx, ey = py - qy, ez = pz - qz;
      float d2 = __fadd_rn(__fadd_rn(__fmul_rn(ex, ex), __fmul_rn(ey, ey)), __fmul_rn(ez, ez));
      if (d2 < RQ && n < 16) {
        bpos[ql][n * 3 + 0] = px;
        bpos[ql][n * 3 + 1] = py;
        bpos[ql][n * 3 + 2] = pz;
        n++;
      }
    }
    bcnt[ql] = n;
  }
  __syncthreads();

  float* Xr = X + (size_t)q * 256;

  if (role == 0) {
    // merge B's hits in index order until 16
    int nB = bcnt[ql];
    for (int e = 0; e < nB; ++e) {
      if (n >= 16) break;
      float px = bpos[ql][e * 3 + 0], py = bpos[ql][e * 3 + 1], pz = bpos[ql][e * 3 + 2];
      float ex = px - qx, ey = py - qy, ez = pz - qz;
      n++;
      sdx += ex; sdy += ey; sdz += ez;
      s2x += ex * ex; s2y += ey * ey; s2z += ez * ez;
      float d2 = ex * ex + ey * ey + ez * ez;
      float dn = sqrtf(d2);
      float t = dn * 10.0f;
      float w = fmaxf(1.0f - t * t * t, 0.0f);
      sw += w; swx += w * px; swy += w * py; swz += w * pz;
    }

    float fn = (float)n;
    // padding slots: nbrs = 0 -> dn = ||q||, contributes (16-n)*wpad to density
    float tq = sqrtf(qx * qx + qy * qy + qz * qz) * 10.0f;
    float wpad = fmaxf(1.0f - tq * tq * tq, 0.0f);
    float density = sw + (16.0f - fn) * wpad;
    float invd = 1.0f / (density + 1e-12f);
    float spx = swx * invd, spy = swy * invd, spz = swz * invd;

    float invn = 1.0f / (fn + 1e-12f);
    float mx = sdx * invn, my = sdy * invn, mz = sdz * invn;
    float vx = fmaxf((s2x - 2.0f * mx * sdx + fn * mx * mx) * invn, 0.0f);
    float vy = fmaxf((s2y - 2.0f * my * sdy + fn * my * my) * invn, 0.0f);
    float vz = fmaxf((s2z - 2.0f * mz * sdz + fn * mz * mz) * invn, 0.0f);

    float dxx = spx - ro[0], dyy = spy - ro[1], dzz = spz - ro[2];
    float il = 1.0f / sqrtf(dxx * dxx + dyy * dyy + dzz * dzz);
    float dirx = dxx * il, diry = dyy * il, dirz = dzz * il;

    posenc1(Xr + 63, density, 4);           // density_emb   [63..71]
    posenc3(Xr + 72, spx, spy, spz, 10);    // smoothed_emb  [72..134]
    posenc3(Xr + 135, vx, vy, vz, 10);      // var_emb       [135..197]
    posenc3(Xr + 225, dirx, diry, dirz, 4); // dirs_emb      [225..251]
  } else {
    posenc3(Xr + 0, qx, qy, qz, 10);        // hit_pos_emb   [0..62]
    int r = q / 48;
    posenc3(Xr + 198, rays[6 * r + 3], rays[6 * r + 4], rays[6 * r + 5], 4); // [198..224]
    Xr[252] = normals[3 * q + 0];
    Xr[253] = normals[3 * q + 1];
    Xr[254] = normals[3 * q + 2];
    Xr[255] = 0.0f;                         // padding column
  }
}

// ---------------------------------------------------------------------------
// Kernel 3: split-bf16 MFMA GEMM (precision-doubled).
// C[M,256] = A[M,K](fp32) * W[N,K]^T + bias, optional relu, fp32 out.
// A is split on the fly into hi/lo bf16; W comes pre-split (planes Bh/Bl).
// acc += Ah*Bh + Ah*Bl + Al*Bh   (Al*Bl dropped, ~2^-18 rel).
// A columns [0,256) come from Aa, [256,512) from Ab (both row-stride 256).
// 128x128 tile, BK=32, 4 waves (2x2), 16x16x32 MFMA.
// ---------------------------------------------------------------------------
__global__ __launch_bounds__(256) void gemm3(
    const float* __restrict__ Aa,
    const float* __restrict__ Ab,
    const unsigned short* __restrict__ Bh,
    const unsigned short* __restrict__ Bl,
    const float* __restrict__ bias,
    float* __restrict__ C,
    int K, int ksteps, int relu)
{
  __shared__ alignas(16) unsigned short Ash[128 * 32];
  __shared__ alignas(16) unsigned short Asl[128 * 32];
  __shared__ alignas(16) unsigned short Bsh[128 * 32];
  __shared__ alignas(16) unsigned short Bsl[128 * 32];

  const int tid = threadIdx.x;
  const int lane = tid & 63, wave = tid >> 6;
  const int wm = wave >> 1, wn = wave & 1;
  const int bm = blockIdx.x * 128, bn = blockIdx.y * 128;
  const int ra = tid >> 1, ca = (tid & 1) * 16;  // A staging: row, 16-col group
  const int rb = tid >> 2, qb = (tid & 3) * 8;   // B staging: row, 8-col group
  const int koff = (lane >> 4) * 8;

  f32x4 acc[4][4] = {};

  for (int kt = 0; kt < ksteps; ++kt) {
    const int k0 = kt * 32;
    __syncthreads();

    // ---- stage A: 16 fp32 -> hi/lo bf16 ----
    {
      const int c0 = k0 + ca;
      const float* src = (c0 < 256) ? (Aa + (size_t)(bm + ra) * 256 + c0)
                                    : (Ab + (size_t)(bm + ra) * 256 + (c0 - 256));
      float vv[16];
      *(float4*)&vv[0]  = ((const float4*)src)[0];
      *(float4*)&vv[4]  = ((const float4*)src)[1];
      *(float4*)&vv[8]  = ((const float4*)src)[2];
      *(float4*)&vv[12] = ((const float4*)src)[3];
      unsigned ph[8], pl[8];
      #pragma unroll
      for (int t = 0; t < 8; ++t) {
        float a0 = vv[2 * t], a1 = vv[2 * t + 1];
        unsigned short h0 = f2b(a0), h1 = f2b(a1);
        unsigned short l0 = f2b(a0 - b2f(h0)), l1 = f2b(a1 - b2f(h1));
        ph[t] = (unsigned)h0 | ((unsigned)h1 << 16);
        pl[t] = (unsigned)l0 | ((unsigned)l1 << 16);
      }
      ((uint4*)&Ash[ra * 32 + ca])[0] = make_uint4(ph[0], ph[1], ph[2], ph[3]);
      ((uint4*)&Ash[ra * 32 + ca])[1] = make_uint4(ph[4], ph[5], ph[6], ph[7]);
      ((uint4*)&Asl[ra * 32 + ca])[0] = make_uint4(pl[0], pl[1], pl[2], pl[3]);
      ((uint4*)&Asl[ra * 32 + ca])[1] = make_uint4(pl[4], pl[5], pl[6], pl[7]);
    }
    // ---- stage B: pre-split bf16 planes ----
    {
      uint4 h0 = *(const uint4*)(Bh + (size_t)(bn + rb) * K + k0 + qb);
      uint4 h1 = *(const uint4*)(Bh + (size_t)(bn + rb + 64) * K + k0 + qb);
      uint4 l0 = *(const uint4*)(Bl + (size_t)(bn + rb) * K + k0 + qb);
      uint4 l1 = *(const uint4*)(Bl + (size_t)(bn + rb + 64) * K + k0 + qb);
      *(uint4*)&Bsh[rb * 32 + qb] = h0;
      *(uint4*)&Bsh[(rb + 64) * 32 + qb] = h1;
      *(uint4*)&Bsl[rb * 32 + qb] = l0;
      *(uint4*)&Bsl[(rb + 64) * 32 + qb] = l1;
    }
    __syncthreads();

    bf16x8 ah[4], al[4], bh[4], bl[4];
    #pragma unroll
    for (int i = 0; i < 4; ++i) {
      const int ao = (wm * 64 + i * 16 + (lane & 15)) * 32 + koff;
      const int bo = (wn * 64 + i * 16 + (lane & 15)) * 32 + koff;
      ah[i] = __builtin_bit_cast(bf16x8, *(const uint4*)&Ash[ao]);
      al[i] = __builtin_bit_cast(bf16x8, *(const uint4*)&Asl[ao]);
      bh[i] = __builtin_bit_cast(bf16x8, *(const uint4*)&Bsh[bo]);
      bl[i] = __builtin_bit_cast(bf16x8, *(const uint4*)&Bsl[bo]);
    }
    #pragma unroll
    for (int i = 0; i < 4; ++i)
      #pragma unroll
      for (int j = 0; j < 4; ++j) {
        acc[i][j] = __builtin_amdgcn_mfma_f32_16x16x32_bf16(ah[i], bh[j], acc[i][j], 0, 0, 0);
        acc[i][j] = __builtin_amdgcn_mfma_f32_16x16x32_bf16(ah[i], bl[j], acc[i][j], 0, 0, 0);
        acc[i][j] = __builtin_amdgcn_mfma_f32_16x16x32_bf16(al[i], bh[j], acc[i][j], 0, 0, 0);
      }
  }

  // epilogue: bias + relu + fp32 store. C/D layout: col=lane&15, row=(lane>>4)*4+r
  float bv[4];
  #pragma unroll
  for (int j = 0; j < 4; ++j) bv[j] = bias[bn + wn * 64 + j * 16 + (lane & 15)];
  #pragma unroll
  for (int i = 0; i < 4; ++i) {
    int mrow = bm + wm * 64 + i * 16 + ((lane >> 4) * 4);
    #pragma unroll
    for (int r = 0; r < 4; ++r) {
      size_t rowoff = (size_t)(mrow + r) * 256;
      #pragma unroll
      for (int j = 0; j < 4; ++j) {
        float v = acc[i][j][r] + bv[j];
        if (relu) v = fmaxf(v, 0.0f);
        C[rowoff + bn + wn * 64 + j * 16 + (lane & 15)] = v;
      }
    }
  }
}

// ---------------------------------------------------------------------------
// Kernel 4: final layer (256 -> 3) + sigmoid, fp32
// ---------------------------------------------------------------------------
__global__ __launch_bounds__(256) void final_kernel(
    const float* __restrict__ H,            // [24576,256] fp32
    const float* __restrict__ W3,           // [3,256]
    const float* __restrict__ b3,           // [3]
    float* __restrict__ out)                // [24576,3]
{
  __shared__ float w3s[768];
  const int tid = threadIdx.x;
  w3s[tid] = W3[tid];
  w3s[tid + 256] = W3[tid + 256];
  w3s[tid + 512] = W3[tid + 512];
  __syncthreads();

  const int row = blockIdx.x * 256 + tid;
  const float* h = H + (size_t)row * 256;
  float a0 = 0, a1 = 0, a2 = 0;
  #pragma unroll 8
  for (int k = 0; k < 256; k += 4) {
    float4 v = *(const float4*)(h + k);
    a0 = fmaf(v.x, w3s[k], a0);       a0 = fmaf(v.y, w3s[k + 1], a0);
    a0 = fmaf(v.z, w3s[k + 2], a0);   a0 = fmaf(v.w, w3s[k + 3], a0);
    a1 = fmaf(v.x, w3s[256 + k], a1); a1 = fmaf(v.y, w3s[256 + k + 1], a1);
    a1 = fmaf(v.z, w3s[256 + k + 2], a1); a1 = fmaf(v.w, w3s[256 + k + 3], a1);
    a2 = fmaf(v.x, w3s[512 + k], a2); a2 = fmaf(v.y, w3s[512 + k + 1], a2);
    a2 = fmaf(v.z, w3s[512 + k + 2], a2); a2 = fmaf(v.w, w3s[512 + k + 3], a2);
  }
  a0 += b3[0]; a1 += b3[1]; a2 += b3[2];
  out[3 * (size_t)row + 0] = 1.0f / (1.0f + expf(-a0));
  out[3 * (size_t)row + 1] = 1.0f / (1.0f + expf(-a1));
  out[3 * (size_t)row + 2] = 1.0f / (1.0f + expf(-a2));
}

// ---------------------------------------------------------------------------
extern "C" void kernel_launch(void* const* d_in, const int* in_sizes, int n_in,
                              void* d_out, int out_size, void* d_ws, size_t ws_size,
                              hipStream_t stream) {
  const float* points  = (const float*)d_in[0];
  const float* normals = (const float*)d_in[1];
  // d_in[2] view_dirs — unused by reference
  const float* fvec    = (const float*)d_in[3];
  // d_in[4] indices — unused
  const float* parts   = (const float*)d_in[5];
  const float* rays    = (const float*)d_in[6];
  const float* ro      = (const float*)d_in[7];
  const float* W0 = (const float*)d_in[8];
  const float* b0 = (const float*)d_in[9];
  const float* W1 = (const float*)d_in[10];
  const float* b1 = (const float*)d_in[11];
  const float* W2 = (const float*)d_in[12];
  const float* b2 = (const float*)d_in[13];
  const float* W3 = (const float*)d_in[14];
  const float* b3 = (const float*)d_in[15];

  char* ws = (char*)d_ws;
  float* X  = (float*)(ws);               // [24576,256] fp32 = 25165824 B
  float* H1 = (float*)(ws + 25165824);    // [24576,256] fp32
  float* H2 = (float*)(ws);               // alias X (dead after L0)
  float* H3 = (float*)(ws + 25165824);    // alias H1 (dead after L1)
  unsigned short* w0h = (unsigned short*)(ws + 50331648);  // 131072 elems
  unsigned short* w0l = (unsigned short*)(ws + 50593792);
  unsigned short* w1h = (unsigned short*)(ws + 50855936);  // 65536 elems
  unsigned short* w1l = (unsigned short*)(ws + 50987008);
  unsigned short* w2h = (unsigned short*)(ws + 51118080);
  unsigned short* w2l = (unsigned short*)(ws + 51249152);
  float* out = (float*)d_out;

  prep_weights<<<1024, 256, 0, stream>>>(W0, W1, W2, w0h, w0l, w1h, w1l, w2h, w2l);
  feat_kernel<<<384, 128, 0, stream>>>(points, normals, parts, rays, ro, X);
  gemm3<<<dim3(192, 2), 256, 0, stream>>>(X, fvec, w0h, w0l, b0, H1, 512, 16, 1);
  gemm3<<<dim3(192, 2), 256, 0, stream>>>(H1, H1, w1h, w1l, b1, H2, 256, 8, 1);
  gemm3<<<dim3(192, 2), 256, 0, stream>>>(H2, H2, w2h, w2l, b2, H3, 256, 8, 1);
  final_kernel<<<96, 256, 0, stream>>>(H3, W3, b3, out);
}

// Round 3
// 243.183 us; speedup vs baseline: 1.5473x; 1.5473x over previous
//
#include <hip/hip_runtime.h>

typedef __bf16 bf16x8 __attribute__((ext_vector_type(8)));
typedef float f32x4 __attribute__((ext_vector_type(4)));

__device__ __forceinline__ unsigned short f2b(float f) {
  unsigned u = __builtin_bit_cast(unsigned, f);
  u = (u + 0x7FFFu + ((u >> 16) & 1u)) >> 16;
  return (unsigned short)u;
}
__device__ __forceinline__ float b2f(unsigned short h) {
  return __builtin_bit_cast(float, (unsigned)h << 16);
}

// async global->LDS, 16B per lane. LDS dst must be wave-uniform base + lane*16.
__device__ __forceinline__ void glds16(const unsigned short* g, unsigned short* l) {
  __builtin_amdgcn_global_load_lds(
      (const __attribute__((address_space(1))) unsigned*)g,
      (__attribute__((address_space(3))) unsigned*)l, 16, 0, 0);
}

// ---------------------------------------------------------------------------
// Column decode table for feat epilogue: col -> (src scalar idx, freq, kind)
// kind: 0 raw, 1 sin, 2 cos, 3 zero.  enc = src | f<<5 | kind<<9
// ---------------------------------------------------------------------------
struct FT {
  unsigned short v[256];
  static constexpr unsigned short enc(int s, int f, int k) {
    return (unsigned short)(s | (f << 5) | (k << 9));
  }
  constexpr void p3(int base, int F, int src) {
    v[base + 0] = enc(src + 0, 0, 0);
    v[base + 1] = enc(src + 1, 0, 0);
    v[base + 2] = enc(src + 2, 0, 0);
    for (int f = 0; f < F; ++f)
      for (int r = 0; r < 6; ++r) {
        int comp = (r < 3) ? r : r - 3;
        v[base + 3 + f * 6 + r] = enc(src + comp, f, (r < 3) ? 1 : 2);
      }
  }
  constexpr void p1(int base, int F, int src) {
    v[base] = enc(src, 0, 0);
    for (int f = 0; f < F; ++f) {
      v[base + 1 + 2 * f] = enc(src, f, 1);
      v[base + 2 + 2 * f] = enc(src, f, 2);
    }
  }
  constexpr FT() : v{} {
    p3(0, 10, 0);     // hit_pos_emb   (q)          [0..62]
    p1(63, 4, 3);     // density_emb                [63..71]
    p3(72, 10, 4);    // smoothed_emb  (sp)         [72..134]
    p3(135, 10, 7);   // var_emb       (var)        [135..197]
    p3(198, 4, 10);   // hit_dir_emb   (ray dir)    [198..224]
    p3(225, 4, 13);   // dirs_emb      (dir)        [225..251]
    v[252] = enc(16, 0, 0);  // normals
    v[253] = enc(17, 0, 0);
    v[254] = enc(18, 0, 0);
    v[255] = enc(0, 0, 3);   // pad col
  }
};
__constant__ FT ftab = FT();

// ---------------------------------------------------------------------------
// Kernel 1: weight prep fp32 -> split bf16 planes (hi + lo).
// W0 [256,511] reordered/padded to [256,512]: col 255 = 0, cols 256..511 =
// orig 255..510 (the fvec block).
// ---------------------------------------------------------------------------
__global__ __launch_bounds__(256) void prep_weights(
    const float* __restrict__ W0, const float* __restrict__ W1,
    const float* __restrict__ W2,
    unsigned short* __restrict__ w0h, unsigned short* __restrict__ w0l,
    unsigned short* __restrict__ w1h, unsigned short* __restrict__ w1l,
    unsigned short* __restrict__ w2h, unsigned short* __restrict__ w2l)
{
  int i = blockIdx.x * 256 + threadIdx.x;   // 0 .. 262143
  float v;
  unsigned short* ph;
  unsigned short* pl;
  int j;
  if (i < 131072) {
    int n = i >> 9, c = i & 511;
    v = (c < 255) ? W0[n * 511 + c] : ((c == 255) ? 0.0f : W0[n * 511 + (c - 1)]);
    ph = w0h; pl = w0l; j = i;
  } else if (i < 196608) {
    j = i - 131072; v = W1[j]; ph = w1h; pl = w1l;
  } else {
    j = i - 196608; v = W2[j]; ph = w2h; pl = w2l;
  }
  unsigned short h = f2b(v);
  ph[j] = h;
  pl[j] = f2b(v - b2f(h));
}

// ---------------------------------------------------------------------------
// Kernel 2: ball query + features. 1 wave per query, 16 queries/block.
// Lane i scans particles {j*64+i}; first-16-by-index via ballot prefix.
// Output: Xh/Xl bf16 planes [24576, 256] (cols 0..254 features, 255 = 0).
// ---------------------------------------------------------------------------
__global__ __launch_bounds__(1024) void feat_kernel(
    const float* __restrict__ points,   // [24576,3]
    const float* __restrict__ normals,  // [24576,3]
    const float* __restrict__ parts,    // [4096,3]
    const float* __restrict__ rays,     // [512,6]
    const float* __restrict__ ro,       // [3]
    unsigned short* __restrict__ Xh,
    unsigned short* __restrict__ Xl)
{
  __shared__ float2 pxy[4096];          // 32 KB
  __shared__ float  pzs[4096];          // 16 KB
  __shared__ float  sdata[16][20];      // per-wave stat broadcast

  const int tid = threadIdx.x;
  for (int j = tid; j < 4096; j += 1024) {
    pxy[j] = make_float2(parts[3 * j + 0], parts[3 * j + 1]);
    pzs[j] = parts[3 * j + 2];
  }
  __syncthreads();

  const int lane = tid & 63, wv = tid >> 6;
  const int q = blockIdx.x * 16 + wv;
  const float qx = points[3 * q], qy = points[3 * q + 1], qz = points[3 * q + 2];
  const float RQ = 0.1f * 0.1f;

  int nAcc = 0, total = 0;
  float sdx = 0, sdy = 0, sdz = 0;
  float s2x = 0, s2y = 0, s2z = 0;
  float sw = 0, swx = 0, swy = 0, swz = 0;

  for (int jr = 0; jr < 64; ++jr) {
    float2 xy = pxy[jr * 64 + lane];
    float z = pzs[jr * 64 + lane];
    float ex = xy.x - qx, ey = xy.y - qy, ez = z - qz;
    float d2 = __fadd_rn(__fadd_rn(__fmul_rn(ex, ex), __fmul_rn(ey, ey)), __fmul_rn(ez, ez));
    bool hit = d2 < RQ;
    unsigned long long m = __ballot(hit);
    int pos = __builtin_amdgcn_mbcnt_hi((unsigned)(m >> 32),
              __builtin_amdgcn_mbcnt_lo((unsigned)m, 0u));
    if (hit && (total + pos < 16)) {
      nAcc++;
      sdx += ex; sdy += ey; sdz += ez;
      s2x += ex * ex; s2y += ey * ey; s2z += ez * ez;
      float dn = sqrtf(d2);
      float t = dn * 10.0f;
      float w = fmaxf(1.0f - t * t * t, 0.0f);
      sw += w; swx += w * xy.x; swy += w * xy.y; swz += w * z;
    }
    total += __popcll(m);
    if (total >= 16) break;
  }

  // wave butterfly reductions (all lanes end with the sum)
  #define WRED(x) { _Pragma("unroll") for (int o = 32; o; o >>= 1) x += __shfl_xor(x, o, 64); }
  float fn = (float)nAcc;
  WRED(fn); WRED(sdx); WRED(sdy); WRED(sdz);
  WRED(s2x); WRED(s2y); WRED(s2z);
  WRED(sw); WRED(swx); WRED(swy); WRED(swz);
  #undef WRED

  // derived stats (computed redundantly on all lanes)
  float tq = sqrtf(qx * qx + qy * qy + qz * qz) * 10.0f;
  float wpad = fmaxf(1.0f - tq * tq * tq, 0.0f);
  float density = sw + (16.0f - fn) * wpad;
  float invd = 1.0f / (density + 1e-12f);
  float spx = swx * invd, spy = swy * invd, spz = swz * invd;

  float invn = 1.0f / (fn + 1e-12f);
  float mx = sdx * invn, my = sdy * invn, mz = sdz * invn;
  float vx = fmaxf((s2x - 2.0f * mx * sdx + fn * mx * mx) * invn, 0.0f);
  float vy = fmaxf((s2y - 2.0f * my * sdy + fn * my * my) * invn, 0.0f);
  float vz = fmaxf((s2z - 2.0f * mz * sdz + fn * mz * mz) * invn, 0.0f);

  float dxx = spx - ro[0], dyy = spy - ro[1], dzz = spz - ro[2];
  float il = 1.0f / sqrtf(dxx * dxx + dyy * dyy + dzz * dzz);

  if (lane == 0) {
    float* s = sdata[wv];
    s[0] = qx; s[1] = qy; s[2] = qz; s[3] = density;
    s[4] = spx; s[5] = spy; s[6] = spz;
    s[7] = vx; s[8] = vy; s[9] = vz;
    int r = q / 48;
    s[10] = rays[6 * r + 3]; s[11] = rays[6 * r + 4]; s[12] = rays[6 * r + 5];
    s[13] = dxx * il; s[14] = dyy * il; s[15] = dzz * il;
    s[16] = normals[3 * q + 0]; s[17] = normals[3 * q + 1]; s[18] = normals[3 * q + 2];
  }
  __syncthreads();

  const size_t base = (size_t)q * 256;
  #pragma unroll
  for (int it = 0; it < 4; ++it) {
    int c = it * 64 + lane;
    int e = ftab.v[c];
    float sv = sdata[wv][e & 31];
    float arg = sv * (float)(1 << ((e >> 5) & 15));
    float sn, cs;
    sincosf(arg, &sn, &cs);
    int kind = e >> 9;
    float val = (kind == 0) ? sv : (kind == 1 ? sn : (kind == 2 ? cs : 0.0f));
    unsigned short h = f2b(val);
    Xh[base + c] = h;
    Xl[base + c] = f2b(val - b2f(h));
  }
}

// ---------------------------------------------------------------------------
// Kernel 3: split-bf16 MFMA GEMM with plane inputs.
// C = A[M,K]*W[N,K]^T + bias (+relu), A/W as hi+lo bf16 planes, out planes.
// A cols < kfp: planes Ah/Al (row stride 256). cols >= kfp: fp32 Afp
// (row stride 256, col offset -kfp), split in staging.
// acc += Ah*Bh + Ah*Bl + Al*Bh.  128x128 tile, BK=32, 4 waves.
// ---------------------------------------------------------------------------
__global__ __launch_bounds__(256) void gemm_planes(
    const unsigned short* __restrict__ Ah, const unsigned short* __restrict__ Al,
    const float* __restrict__ Afp,
    const unsigned short* __restrict__ Bh, const unsigned short* __restrict__ Bl,
    const float* __restrict__ bias,
    unsigned short* __restrict__ Ch, unsigned short* __restrict__ Cl,
    int K, int ksteps, int kfp, int relu)
{
  __shared__ alignas(16) unsigned short Ash[128 * 32];
  __shared__ alignas(16) unsigned short Asl[128 * 32];
  __shared__ alignas(16) unsigned short Bsh[128 * 32];
  __shared__ alignas(16) unsigned short Bsl[128 * 32];

  const int tid = threadIdx.x;
  const int lane = tid & 63, wave = tid >> 6;
  const int wm = wave >> 1, wn = wave & 1;
  const int bm = blockIdx.x * 128, bn = blockIdx.y * 128;
  const int r1 = tid >> 2, o1 = (tid & 3) * 8;   // plane staging map
  const int ra = tid >> 1, ca = (tid & 1) * 16;  // fp32 staging map
  const int koff = (lane >> 4) * 8;

  f32x4 acc[4][4] = {};

  for (int kt = 0; kt < ksteps; ++kt) {
    const int k0 = kt * 32;
    __syncthreads();

    if (k0 < kfp) {
      // A from bf16 planes, async direct-to-LDS
      glds16(Ah + (size_t)(bm + r1) * 256 + k0 + o1, &Ash[tid * 8]);
      glds16(Ah + (size_t)(bm + r1 + 64) * 256 + k0 + o1, &Ash[2048 + tid * 8]);
      glds16(Al + (size_t)(bm + r1) * 256 + k0 + o1, &Asl[tid * 8]);
      glds16(Al + (size_t)(bm + r1 + 64) * 256 + k0 + o1, &Asl[2048 + tid * 8]);
    } else {
      // A from fp32 source, split in registers
      const float* src = Afp + (size_t)(bm + ra) * 256 + (k0 - kfp) + ca;
      float vv[16];
      *(float4*)&vv[0]  = ((const float4*)src)[0];
      *(float4*)&vv[4]  = ((const float4*)src)[1];
      *(float4*)&vv[8]  = ((const float4*)src)[2];
      *(float4*)&vv[12] = ((const float4*)src)[3];
      unsigned ph[8], pl[8];
      #pragma unroll
      for (int t = 0; t < 8; ++t) {
        float a0 = vv[2 * t], a1 = vv[2 * t + 1];
        unsigned short h0 = f2b(a0), h1 = f2b(a1);
        unsigned short l0 = f2b(a0 - b2f(h0)), l1 = f2b(a1 - b2f(h1));
        ph[t] = (unsigned)h0 | ((unsigned)h1 << 16);
        pl[t] = (unsigned)l0 | ((unsigned)l1 << 16);
      }
      ((uint4*)&Ash[ra * 32 + ca])[0] = make_uint4(ph[0], ph[1], ph[2], ph[3]);
      ((uint4*)&Ash[ra * 32 + ca])[1] = make_uint4(ph[4], ph[5], ph[6], ph[7]);
      ((uint4*)&Asl[ra * 32 + ca])[0] = make_uint4(pl[0], pl[1], pl[2], pl[3]);
      ((uint4*)&Asl[ra * 32 + ca])[1] = make_uint4(pl[4], pl[5], pl[6], pl[7]);
    }
    glds16(Bh + (size_t)(bn + r1) * K + k0 + o1, &Bsh[tid * 8]);
    glds16(Bh + (size_t)(bn + r1 + 64) * K + k0 + o1, &Bsh[2048 + tid * 8]);
    glds16(Bl + (size_t)(bn + r1) * K + k0 + o1, &Bsl[tid * 8]);
    glds16(Bl + (size_t)(bn + r1 + 64) * K + k0 + o1, &Bsl[2048 + tid * 8]);
    __syncthreads();

    bf16x8 ah[4], al[4], bh[4], bl[4];
    #pragma unroll
    for (int i = 0; i < 4; ++i) {
      const int ao = (wm * 64 + i * 16 + (lane & 15)) * 32 + koff;
      const int bo = (wn * 64 + i * 16 + (lane & 15)) * 32 + koff;
      ah[i] = __builtin_bit_cast(bf16x8, *(const uint4*)&Ash[ao]);
      al[i] = __builtin_bit_cast(bf16x8, *(const uint4*)&Asl[ao]);
      bh[i] = __builtin_bit_cast(bf16x8, *(const uint4*)&Bsh[bo]);
      bl[i] = __builtin_bit_cast(bf16x8, *(const uint4*)&Bsl[bo]);
    }
    #pragma unroll
    for (int i = 0; i < 4; ++i)
      #pragma unroll
      for (int j = 0; j < 4; ++j) {
        acc[i][j] = __builtin_amdgcn_mfma_f32_16x16x32_bf16(ah[i], bh[j], acc[i][j], 0, 0, 0);
        acc[i][j] = __builtin_amdgcn_mfma_f32_16x16x32_bf16(ah[i], bl[j], acc[i][j], 0, 0, 0);
        acc[i][j] = __builtin_amdgcn_mfma_f32_16x16x32_bf16(al[i], bh[j], acc[i][j], 0, 0, 0);
      }
  }

  // epilogue: bias + relu, split to hi/lo planes. C/D: col=lane&15, row=(lane>>4)*4+r
  float bv[4];
  #pragma unroll
  for (int j = 0; j < 4; ++j) bv[j] = bias[bn + wn * 64 + j * 16 + (lane & 15)];
  #pragma unroll
  for (int i = 0; i < 4; ++i) {
    int mrow = bm + wm * 64 + i * 16 + ((lane >> 4) * 4);
    #pragma unroll
    for (int r = 0; r < 4; ++r) {
      size_t rowoff = (size_t)(mrow + r) * 256;
      #pragma unroll
      for (int j = 0; j < 4; ++j) {
        float v = acc[i][j][r] + bv[j];
        if (relu) v = fmaxf(v, 0.0f);
        unsigned short h = f2b(v);
        size_t o = rowoff + bn + wn * 64 + j * 16 + (lane & 15);
        Ch[o] = h;
        Cl[o] = f2b(v - b2f(h));
      }
    }
  }
}

// ---------------------------------------------------------------------------
// Kernel 4: final layer (256 -> 3) + sigmoid, fp32 from hi/lo planes
// ---------------------------------------------------------------------------
__global__ __launch_bounds__(256) void final_kernel(
    const unsigned short* __restrict__ Hh, const unsigned short* __restrict__ Hl,
    const float* __restrict__ W3, const float* __restrict__ b3,
    float* __restrict__ out)
{
  __shared__ float w3s[768];
  const int tid = threadIdx.x;
  w3s[tid] = W3[tid];
  w3s[tid + 256] = W3[tid + 256];
  w3s[tid + 512] = W3[tid + 512];
  __syncthreads();

  const int row = blockIdx.x * 256 + tid;
  const unsigned short* hh = Hh + (size_t)row * 256;
  const unsigned short* hl = Hl + (size_t)row * 256;
  float a0 = 0, a1 = 0, a2 = 0;
  #pragma unroll 4
  for (int k = 0; k < 256; k += 8) {
    uint4 uh = *(const uint4*)(hh + k);
    uint4 ul = *(const uint4*)(hl + k);
    unsigned wh[4] = {uh.x, uh.y, uh.z, uh.w};
    unsigned wl[4] = {ul.x, ul.y, ul.z, ul.w};
    #pragma unroll
    for (int t = 0; t < 4; ++t) {
      float e0 = __builtin_bit_cast(float, wh[t] << 16) +
                 __builtin_bit_cast(float, wl[t] << 16);
      float e1 = __builtin_bit_cast(float, wh[t] & 0xFFFF0000u) +
                 __builtin_bit_cast(float, wl[t] & 0xFFFF0000u);
      int kk = k + 2 * t;
      a0 = fmaf(e0, w3s[kk], a0);        a0 = fmaf(e1, w3s[kk + 1], a0);
      a1 = fmaf(e0, w3s[256 + kk], a1);  a1 = fmaf(e1, w3s[256 + kk + 1], a1);
      a2 = fmaf(e0, w3s[512 + kk], a2);  a2 = fmaf(e1, w3s[512 + kk + 1], a2);
    }
  }
  a0 += b3[0]; a1 += b3[1]; a2 += b3[2];
  out[3 * (size_t)row + 0] = 1.0f / (1.0f + expf(-a0));
  out[3 * (size_t)row + 1] = 1.0f / (1.0f + expf(-a1));
  out[3 * (size_t)row + 2] = 1.0f / (1.0f + expf(-a2));
}

// ---------------------------------------------------------------------------
extern "C" void kernel_launch(void* const* d_in, const int* in_sizes, int n_in,
                              void* d_out, int out_size, void* d_ws, size_t ws_size,
                              hipStream_t stream) {
  const float* points  = (const float*)d_in[0];
  const float* normals = (const float*)d_in[1];
  const float* fvec    = (const float*)d_in[3];
  const float* parts   = (const float*)d_in[5];
  const float* rays    = (const float*)d_in[6];
  const float* ro      = (const float*)d_in[7];
  const float* W0 = (const float*)d_in[8];
  const float* b0 = (const float*)d_in[9];
  const float* W1 = (const float*)d_in[10];
  const float* b1 = (const float*)d_in[11];
  const float* W2 = (const float*)d_in[12];
  const float* b2 = (const float*)d_in[13];
  const float* W3 = (const float*)d_in[14];
  const float* b3 = (const float*)d_in[15];

  char* ws = (char*)d_ws;
  unsigned short* Xh  = (unsigned short*)(ws);              // [24576,256]
  unsigned short* Xl  = (unsigned short*)(ws + 12582912);
  unsigned short* H1h = (unsigned short*)(ws + 25165824);
  unsigned short* H1l = (unsigned short*)(ws + 37748736);
  unsigned short* H2h = Xh;    // X dead after L0
  unsigned short* H2l = Xl;
  unsigned short* H3h = H1h;   // H1 dead after L1
  unsigned short* H3l = H1l;
  unsigned short* w0h = (unsigned short*)(ws + 50331648);
  unsigned short* w0l = (unsigned short*)(ws + 50593792);
  unsigned short* w1h = (unsigned short*)(ws + 50855936);
  unsigned short* w1l = (unsigned short*)(ws + 50987008);
  unsigned short* w2h = (unsigned short*)(ws + 51118080);
  unsigned short* w2l = (unsigned short*)(ws + 51249152);
  float* out = (float*)d_out;

  prep_weights<<<1024, 256, 0, stream>>>(W0, W1, W2, w0h, w0l, w1h, w1l, w2h, w2l);
  feat_kernel<<<1536, 1024, 0, stream>>>(points, normals, parts, rays, ro, Xh, Xl);
  gemm_planes<<<dim3(192, 2), 256, 0, stream>>>(Xh, Xl, fvec, w0h, w0l, b0, H1h, H1l, 512, 16, 256, 1);
  gemm_planes<<<dim3(192, 2), 256, 0, stream>>>(H1h, H1l, nullptr, w1h, w1l, b1, H2h, H2l, 256, 8, 256, 1);
  gemm_planes<<<dim3(192, 2), 256, 0, stream>>>(H2h, H2l, nullptr, w2h, w2l, b2, H3h, H3l, 256, 8, 256, 1);
  final_kernel<<<96, 256, 0, stream>>>(H3h, H3l, W3, b3, out);
}

// Round 4
// 212.553 us; speedup vs baseline: 1.7702x; 1.1441x over previous
//
#include <hip/hip_runtime.h>

typedef __bf16 bf16x8 __attribute__((ext_vector_type(8)));
typedef float f32x4 __attribute__((ext_vector_type(4)));
typedef unsigned short u16;

__device__ __forceinline__ u16 f2b(float f) {
  unsigned u = __builtin_bit_cast(unsigned, f);
  u = (u + 0x7FFFu + ((u >> 16) & 1u)) >> 16;
  return (u16)u;
}
__device__ __forceinline__ float b2f(u16 h) {
  return __builtin_bit_cast(float, (unsigned)h << 16);
}

// async global->LDS, 16B per lane. dst = wave-uniform base + lane*16.
__device__ __forceinline__ void glds16(const u16* g, u16* l) {
  __builtin_amdgcn_global_load_lds(
      (const __attribute__((address_space(1))) unsigned*)g,
      (__attribute__((address_space(3))) unsigned*)l, 16, 0, 0);
}

// ---------------------------------------------------------------------------
// Swizzled HBM layouts (16B = 8-short units, xor-swizzled for conflict-free
// LDS fragment reads after contiguous staging):
// X (A, BK=64 tiles): elem (q,c): b=q/96, m=q%96, kt=c>>6, cc=c&63,
//   g=cc>>3, j=cc&7, u=m*8+(g^(m&7)); off = b*49152 + kt*6144 + u*8 + j
// W (B, BK=64 tiles): elem (n,c): kt=c>>6, cc=c&63, g=cc>>3, j=cc&7,
//   u=n*8+(g^((n>>1)&7)); off = kt*16384 + u*8 + j
// H (LDS activations): elem (m,k): g=k>>3, j=k&7, u=m*32+(g^(m&7))
// ---------------------------------------------------------------------------
__device__ __forceinline__ int xoff(int b, int m, int c) {
  int kt = c >> 6, cc = c & 63, g = cc >> 3, j = cc & 7;
  int u = m * 8 + (g ^ (m & 7));
  return b * 49152 + kt * 6144 + u * 8 + j;
}

// ---------------------------------------------------------------------------
// Column decode table for feat epilogue: col -> (src scalar idx, freq, kind)
// kind: 0 raw, 1 sin, 2 cos, 3 zero.  enc = src | f<<5 | kind<<9
// ---------------------------------------------------------------------------
struct FT {
  u16 v[256];
  static constexpr u16 enc(int s, int f, int k) {
    return (u16)(s | (f << 5) | (k << 9));
  }
  constexpr void p3(int base, int F, int src) {
    v[base + 0] = enc(src + 0, 0, 0);
    v[base + 1] = enc(src + 1, 0, 0);
    v[base + 2] = enc(src + 2, 0, 0);
    for (int f = 0; f < F; ++f)
      for (int r = 0; r < 6; ++r) {
        int comp = (r < 3) ? r : r - 3;
        v[base + 3 + f * 6 + r] = enc(src + comp, f, (r < 3) ? 1 : 2);
      }
  }
  constexpr void p1(int base, int F, int src) {
    v[base] = enc(src, 0, 0);
    for (int f = 0; f < F; ++f) {
      v[base + 1 + 2 * f] = enc(src, f, 1);
      v[base + 2 + 2 * f] = enc(src, f, 2);
    }
  }
  constexpr FT() : v{} {
    p3(0, 10, 0);     // hit_pos_emb   (q)          [0..62]
    p1(63, 4, 3);     // density_emb                [63..71]
    p3(72, 10, 4);    // smoothed_emb  (sp)         [72..134]
    p3(135, 10, 7);   // var_emb       (var)        [135..197]
    p3(198, 4, 10);   // hit_dir_emb   (ray dir)    [198..224]
    p3(225, 4, 13);   // dirs_emb      (dir)        [225..251]
    v[252] = enc(16, 0, 0);  // normals
    v[253] = enc(17, 0, 0);
    v[254] = enc(18, 0, 0);
    v[255] = enc(0, 0, 3);   // pad col
  }
};
__constant__ FT ftab = FT();

// ---------------------------------------------------------------------------
// Kernel 1: weight prep fp32 -> split bf16 planes in swizzled tile layout.
// W0 [256,511] -> [256,512]: col 255 = 0, cols 256..511 = orig 255..510.
// ---------------------------------------------------------------------------
__global__ __launch_bounds__(256) void prep_weights(
    const float* __restrict__ W0, const float* __restrict__ W1,
    const float* __restrict__ W2,
    u16* __restrict__ w0h, u16* __restrict__ w0l,
    u16* __restrict__ w1h, u16* __restrict__ w1l,
    u16* __restrict__ w2h, u16* __restrict__ w2l)
{
  int i = blockIdx.x * 256 + threadIdx.x;   // 0 .. 262143
  float v; u16 *ph, *pl; int n, c;
  if (i < 131072) {
    n = i >> 9; c = i & 511;
    v = (c < 255) ? W0[n * 511 + c] : ((c == 255) ? 0.0f : W0[n * 511 + (c - 1)]);
    ph = w0h; pl = w0l;
  } else if (i < 196608) {
    int j = i - 131072; n = j >> 8; c = j & 255; v = W1[j]; ph = w1h; pl = w1l;
  } else {
    int j = i - 196608; n = j >> 8; c = j & 255; v = W2[j]; ph = w2h; pl = w2l;
  }
  int kt = c >> 6, cc = c & 63, g = cc >> 3, jj = cc & 7;
  int u = n * 8 + (g ^ ((n >> 1) & 7));
  int off = kt * 16384 + u * 8 + jj;
  u16 h = f2b(v);
  ph[off] = h;
  pl[off] = f2b(v - b2f(h));
}

// ---------------------------------------------------------------------------
// Kernel 2: ball query + features -> swizzled X planes [24576, 512].
// 1 wave/query; lane-interleaved scan; first-16-by-index via ballot prefix.
// Also splits fvec into X cols [256,512).
// ---------------------------------------------------------------------------
__global__ __launch_bounds__(1024) void feat_kernel(
    const float* __restrict__ points, const float* __restrict__ normals,
    const float* __restrict__ fvec, const float* __restrict__ parts,
    const float* __restrict__ rays, const float* __restrict__ ro,
    u16* __restrict__ Xh, u16* __restrict__ Xl)
{
  __shared__ float2 pxy[4096];
  __shared__ float  pzs[4096];
  __shared__ float  sdata[16][20];

  const int tid = threadIdx.x;
  for (int j = tid; j < 4096; j += 1024) {
    pxy[j] = make_float2(parts[3 * j + 0], parts[3 * j + 1]);
    pzs[j] = parts[3 * j + 2];
  }
  __syncthreads();

  const int lane = tid & 63, wv = tid >> 6;
  const int q = blockIdx.x * 16 + wv;
  const float qx = points[3 * q], qy = points[3 * q + 1], qz = points[3 * q + 2];
  const float RQ = 0.1f * 0.1f;

  int nAcc = 0, total = 0;
  float sdx = 0, sdy = 0, sdz = 0;
  float s2x = 0, s2y = 0, s2z = 0;
  float sw = 0, swx = 0, swy = 0, swz = 0;

  for (int jr = 0; jr < 64; ++jr) {
    float2 xy = pxy[jr * 64 + lane];
    float z = pzs[jr * 64 + lane];
    float ex = xy.x - qx, ey = xy.y - qy, ez = z - qz;
    float d2 = __fadd_rn(__fadd_rn(__fmul_rn(ex, ex), __fmul_rn(ey, ey)), __fmul_rn(ez, ez));
    bool hit = d2 < RQ;
    unsigned long long m = __ballot(hit);
    int pos = __builtin_amdgcn_mbcnt_hi((unsigned)(m >> 32),
              __builtin_amdgcn_mbcnt_lo((unsigned)m, 0u));
    if (hit && (total + pos < 16)) {
      nAcc++;
      sdx += ex; sdy += ey; sdz += ez;
      s2x += ex * ex; s2y += ey * ey; s2z += ez * ez;
      float dn = sqrtf(d2);
      float t = dn * 10.0f;
      float w = fmaxf(1.0f - t * t * t, 0.0f);
      sw += w; swx += w * xy.x; swy += w * xy.y; swz += w * z;
    }
    total += __popcll(m);
    if (total >= 16) break;
  }

  #define WRED(x) { _Pragma("unroll") for (int o = 32; o; o >>= 1) x += __shfl_xor(x, o, 64); }
  float fn = (float)nAcc;
  WRED(fn); WRED(sdx); WRED(sdy); WRED(sdz);
  WRED(s2x); WRED(s2y); WRED(s2z);
  WRED(sw); WRED(swx); WRED(swy); WRED(swz);
  #undef WRED

  float tq = sqrtf(qx * qx + qy * qy + qz * qz) * 10.0f;
  float wpad = fmaxf(1.0f - tq * tq * tq, 0.0f);
  float density = sw + (16.0f - fn) * wpad;
  float invd = 1.0f / (density + 1e-12f);
  float spx = swx * invd, spy = swy * invd, spz = swz * invd;

  float invn = 1.0f / (fn + 1e-12f);
  float mx = sdx * invn, my = sdy * invn, mz = sdz * invn;
  float vx = fmaxf((s2x - 2.0f * mx * sdx + fn * mx * mx) * invn, 0.0f);
  float vy = fmaxf((s2y - 2.0f * my * sdy + fn * my * my) * invn, 0.0f);
  float vz = fmaxf((s2z - 2.0f * mz * sdz + fn * mz * mz) * invn, 0.0f);

  float dxx = spx - ro[0], dyy = spy - ro[1], dzz = spz - ro[2];
  float il = 1.0f / sqrtf(dxx * dxx + dyy * dyy + dzz * dzz);

  if (lane == 0) {
    float* s = sdata[wv];
    s[0] = qx; s[1] = qy; s[2] = qz; s[3] = density;
    s[4] = spx; s[5] = spy; s[6] = spz;
    s[7] = vx; s[8] = vy; s[9] = vz;
    int r = q / 48;
    s[10] = rays[6 * r + 3]; s[11] = rays[6 * r + 4]; s[12] = rays[6 * r + 5];
    s[13] = dxx * il; s[14] = dyy * il; s[15] = dzz * il;
    s[16] = normals[3 * q + 0]; s[17] = normals[3 * q + 1]; s[18] = normals[3 * q + 2];
  }
  __syncthreads();

  const int b96 = q / 96, m96 = q % 96;
  #pragma unroll
  for (int it = 0; it < 4; ++it) {
    int c = it * 64 + lane;
    int e = ftab.v[c];
    float sv = sdata[wv][e & 31];
    float arg = sv * (float)(1 << ((e >> 5) & 15));
    float sn, cs;
    sincosf(arg, &sn, &cs);
    int kind = e >> 9;
    float val = (kind == 0) ? sv : (kind == 1 ? sn : (kind == 2 ? cs : 0.0f));
    u16 h = f2b(val);
    int off = xoff(b96, m96, c);
    Xh[off] = h;
    Xl[off] = f2b(val - b2f(h));
  }
  // fvec block -> cols [256, 512)
  {
    float4 v = ((const float4*)(fvec + (size_t)q * 256))[lane];
    float vv[4] = {v.x, v.y, v.z, v.w};
    int off = xoff(b96, m96, 256 + lane * 4);  // 4 consecutive shorts, 8B aligned
    u16 hs[4], ls[4];
    #pragma unroll
    for (int s = 0; s < 4; ++s) {
      hs[s] = f2b(vv[s]);
      ls[s] = f2b(vv[s] - b2f(hs[s]));
    }
    *(uint2*)(Xh + off) = *(uint2*)hs;
    *(uint2*)(Xl + off) = *(uint2*)ls;
  }
}

// ---------------------------------------------------------------------------
// Kernel 3: fused 3-layer split-bf16 MFMA MLP + final 256->3 + sigmoid.
// 256 blocks x 512 thr (8 waves, 2x4 grid, wave tile 48x64), 96 rows/block.
// LDS 160 KB: [0,98304) = L0 A-stage (24.5K, aliased) then H planes;
//             [98304,163840) = B tile (32K hi + 32K lo), w3s aliased at end.
// acc += Ah*Bh + Ah*Bl + Al*Bh per fragment pair.
// ---------------------------------------------------------------------------
__global__ __launch_bounds__(512, 2) void fused_mlp(
    const u16* __restrict__ Xh, const u16* __restrict__ Xl,
    const u16* __restrict__ w0h, const u16* __restrict__ w0l,
    const u16* __restrict__ w1h, const u16* __restrict__ w1l,
    const u16* __restrict__ w2h, const u16* __restrict__ w2l,
    const float* __restrict__ b0, const float* __restrict__ b1,
    const float* __restrict__ b2,
    const float* __restrict__ W3, const float* __restrict__ b3,
    float* __restrict__ out)
{
  extern __shared__ char lds[];
  u16* Ast_h = (u16*)lds;                 // L0 stage (12288 B each plane)
  u16* Ast_l = (u16*)(lds + 12288);
  u16* Hh    = (u16*)lds;                 // 49152 B
  u16* Hl    = (u16*)(lds + 49152);       // 49152 B
  u16* Bsh   = (u16*)(lds + 98304);       // 32768 B
  u16* Bsl   = (u16*)(lds + 131072);      // 32768 B
  float* w3s = (float*)(lds + 98304);     // final phase (B region dead)

  const int tid = threadIdx.x, lane = tid & 63, wv = tid >> 6;
  const int wm = wv >> 2, wn = wv & 3;
  const int blk = blockIdx.x;
  const int l15 = lane & 15, l4 = lane >> 4;

  f32x4 acc[3][4];

  // ======================= L0: K=512, A from global X =======================
  #pragma unroll
  for (int i = 0; i < 3; ++i)
    #pragma unroll
    for (int j = 0; j < 4; ++j) acc[i][j] = (f32x4){0, 0, 0, 0};

  const u16* Xht = Xh + blk * 49152;
  const u16* Xlt = Xl + blk * 49152;

  for (int kt = 0; kt < 8; ++kt) {
    // stage A (24 KB) : 3 chunks/wave
    #pragma unroll
    for (int s = 0; s < 3; ++s) {
      int ch = wv + s * 8;                       // 0..23
      int c12 = (ch < 12) ? ch : ch - 12;
      const u16* src = ((ch < 12) ? Xht : Xlt) + kt * 6144 + c12 * 512 + lane * 8;
      u16* dst = ((ch < 12) ? Ast_h : Ast_l) + c12 * 512 + lane * 8;
      glds16(src, dst);
    }
    // stage B (64 KB): 8 chunks/wave
    #pragma unroll
    for (int s = 0; s < 8; ++s) {
      int ch = wv + s * 8;                       // 0..63
      int c32 = ch & 31;
      const u16* src = ((ch < 32) ? w0h : w0l) + kt * 16384 + c32 * 512 + lane * 8;
      u16* dst = ((ch < 32) ? Bsh : Bsl) + c32 * 512 + lane * 8;
      glds16(src, dst);
    }
    __syncthreads();
    #pragma unroll
    for (int kh = 0; kh < 2; ++kh) {
      bf16x8 a_h[3], a_l[3], bb_h[4], bb_l[4];
      #pragma unroll
      for (int i = 0; i < 3; ++i) {
        int m = wm * 48 + i * 16 + l15;
        int g = kh * 4 + l4;
        int u = m * 8 + (g ^ (m & 7));
        a_h[i] = __builtin_bit_cast(bf16x8, *(const uint4*)(Ast_h + u * 8));
        a_l[i] = __builtin_bit_cast(bf16x8, *(const uint4*)(Ast_l + u * 8));
      }
      #pragma unroll
      for (int j = 0; j < 4; ++j) {
        int n = wn * 64 + j * 16 + l15;
        int g = kh * 4 + l4;
        int u = n * 8 + (g ^ ((n >> 1) & 7));
        bb_h[j] = __builtin_bit_cast(bf16x8, *(const uint4*)(Bsh + u * 8));
        bb_l[j] = __builtin_bit_cast(bf16x8, *(const uint4*)(Bsl + u * 8));
      }
      #pragma unroll
      for (int i = 0; i < 3; ++i)
        #pragma unroll
        for (int j = 0; j < 4; ++j) {
          acc[i][j] = __builtin_amdgcn_mfma_f32_16x16x32_bf16(a_h[i], bb_h[j], acc[i][j], 0, 0, 0);
          acc[i][j] = __builtin_amdgcn_mfma_f32_16x16x32_bf16(a_h[i], bb_l[j], acc[i][j], 0, 0, 0);
          acc[i][j] = __builtin_amdgcn_mfma_f32_16x16x32_bf16(a_l[i], bb_h[j], acc[i][j], 0, 0, 0);
        }
    }
    __syncthreads();
  }

  // epilogue lambda: bias + relu + split-write into H (LDS)
  auto epilogue = [&](const float* bias_) {
    float bv[4];
    #pragma unroll
    for (int j = 0; j < 4; ++j) bv[j] = bias_[wn * 64 + j * 16 + l15];
    #pragma unroll
    for (int i = 0; i < 3; ++i) {
      int mbase = wm * 48 + i * 16 + l4 * 4;
      #pragma unroll
      for (int r = 0; r < 4; ++r) {
        int m = mbase + r;
        #pragma unroll
        for (int j = 0; j < 4; ++j) {
          int n = wn * 64 + j * 16 + l15;
          float v = fmaxf(acc[i][j][r] + bv[j], 0.0f);
          u16 h = f2b(v);
          int u = m * 32 + ((n >> 3) ^ (m & 7));
          int off = u * 8 + (n & 7);
          Hh[off] = h;
          Hl[off] = f2b(v - b2f(h));
        }
      }
    }
  };
  epilogue(b0);

  // ======================= L1, L2: K=256, A from H ==========================
  #pragma unroll 1
  for (int layer = 0; layer < 2; ++layer) {
    const u16* wh_ = (layer == 0) ? w1h : w2h;
    const u16* wl_ = (layer == 0) ? w1l : w2l;
    #pragma unroll
    for (int i = 0; i < 3; ++i)
      #pragma unroll
      for (int j = 0; j < 4; ++j) acc[i][j] = (f32x4){0, 0, 0, 0};

    for (int kt = 0; kt < 4; ++kt) {
      #pragma unroll
      for (int s = 0; s < 8; ++s) {
        int ch = wv + s * 8;
        int c32 = ch & 31;
        const u16* src = ((ch < 32) ? wh_ : wl_) + kt * 16384 + c32 * 512 + lane * 8;
        u16* dst = ((ch < 32) ? Bsh : Bsl) + c32 * 512 + lane * 8;
        glds16(src, dst);
      }
      __syncthreads();
      #pragma unroll
      for (int kh = 0; kh < 2; ++kh) {
        bf16x8 a_h[3], a_l[3], bb_h[4], bb_l[4];
        #pragma unroll
        for (int i = 0; i < 3; ++i) {
          int m = wm * 48 + i * 16 + l15;
          int g = kt * 8 + kh * 4 + l4;
          int u = m * 32 + (g ^ (m & 7));
          a_h[i] = __builtin_bit_cast(bf16x8, *(const uint4*)(Hh + u * 8));
          a_l[i] = __builtin_bit_cast(bf16x8, *(const uint4*)(Hl + u * 8));
        }
        #pragma unroll
        for (int j = 0; j < 4; ++j) {
          int n = wn * 64 + j * 16 + l15;
          int g = kh * 4 + l4;
          int u = n * 8 + (g ^ ((n >> 1) & 7));
          bb_h[j] = __builtin_bit_cast(bf16x8, *(const uint4*)(Bsh + u * 8));
          bb_l[j] = __builtin_bit_cast(bf16x8, *(const uint4*)(Bsl + u * 8));
        }
        #pragma unroll
        for (int i = 0; i < 3; ++i)
          #pragma unroll
          for (int j = 0; j < 4; ++j) {
            acc[i][j] = __builtin_amdgcn_mfma_f32_16x16x32_bf16(a_h[i], bb_h[j], acc[i][j], 0, 0, 0);
            acc[i][j] = __builtin_amdgcn_mfma_f32_16x16x32_bf16(a_h[i], bb_l[j], acc[i][j], 0, 0, 0);
            acc[i][j] = __builtin_amdgcn_mfma_f32_16x16x32_bf16(a_l[i], bb_h[j], acc[i][j], 0, 0, 0);
          }
      }
      __syncthreads();
    }
    epilogue((layer == 0) ? b1 : b2);
  }

  // ======================= final: 256 -> 3 + sigmoid ========================
  for (int i = tid; i < 768; i += 512) w3s[i] = W3[i];
  __syncthreads();

  const float B30 = b3[0], B31 = b3[1], B32 = b3[2];
  for (int rr = 0; rr < 12; ++rr) {
    int m = wv * 12 + rr;
    int g = lane >> 1, j0 = (lane & 1) * 4;
    int u = m * 32 + (g ^ (m & 7));
    uint2 ph_ = *(const uint2*)(Hh + u * 8 + j0);
    uint2 pl_ = *(const uint2*)(Hl + u * 8 + j0);
    float h0 = b2f((u16)(ph_.x & 0xffff)) + b2f((u16)(pl_.x & 0xffff));
    float h1 = b2f((u16)(ph_.x >> 16))    + b2f((u16)(pl_.x >> 16));
    float h2 = b2f((u16)(ph_.y & 0xffff)) + b2f((u16)(pl_.y & 0xffff));
    float h3 = b2f((u16)(ph_.y >> 16))    + b2f((u16)(pl_.y >> 16));
    int kc = lane * 4;
    float4 wa = *(const float4*)(w3s + kc);
    float4 wb = *(const float4*)(w3s + 256 + kc);
    float4 wc = *(const float4*)(w3s + 512 + kc);
    float p0 = fmaf(h3, wa.w, fmaf(h2, wa.z, fmaf(h1, wa.y, h0 * wa.x)));
    float p1 = fmaf(h3, wb.w, fmaf(h2, wb.z, fmaf(h1, wb.y, h0 * wb.x)));
    float p2 = fmaf(h3, wc.w, fmaf(h2, wc.z, fmaf(h1, wc.y, h0 * wc.x)));
    #pragma unroll
    for (int o = 32; o; o >>= 1) {
      p0 += __shfl_xor(p0, o, 64);
      p1 += __shfl_xor(p1, o, 64);
      p2 += __shfl_xor(p2, o, 64);
    }
    if (lane == 0) {
      size_t ro_ = (size_t)(blk * 96 + m) * 3;
      out[ro_ + 0] = 1.0f / (1.0f + expf(-(p0 + B30)));
      out[ro_ + 1] = 1.0f / (1.0f + expf(-(p1 + B31)));
      out[ro_ + 2] = 1.0f / (1.0f + expf(-(p2 + B32)));
    }
  }
}

// ---------------------------------------------------------------------------
extern "C" void kernel_launch(void* const* d_in, const int* in_sizes, int n_in,
                              void* d_out, int out_size, void* d_ws, size_t ws_size,
                              hipStream_t stream) {
  const float* points  = (const float*)d_in[0];
  const float* normals = (const float*)d_in[1];
  const float* fvec    = (const float*)d_in[3];
  const float* parts   = (const float*)d_in[5];
  const float* rays    = (const float*)d_in[6];
  const float* ro      = (const float*)d_in[7];
  const float* W0 = (const float*)d_in[8];
  const float* b0 = (const float*)d_in[9];
  const float* W1 = (const float*)d_in[10];
  const float* b1 = (const float*)d_in[11];
  const float* W2 = (const float*)d_in[12];
  const float* b2 = (const float*)d_in[13];
  const float* W3 = (const float*)d_in[14];
  const float* b3 = (const float*)d_in[15];

  char* ws = (char*)d_ws;
  u16* Xh  = (u16*)(ws);                    // [24576x512] swizzled
  u16* Xl  = (u16*)(ws + 25165824);
  u16* w0h = (u16*)(ws + 50331648);
  u16* w0l = (u16*)(ws + 50593792);
  u16* w1h = (u16*)(ws + 50855936);
  u16* w1l = (u16*)(ws + 50987008);
  u16* w2h = (u16*)(ws + 51118080);
  u16* w2l = (u16*)(ws + 51249152);
  float* out = (float*)d_out;

  (void)hipFuncSetAttribute((const void*)fused_mlp,
                            hipFuncAttributeMaxDynamicSharedMemorySize, 163840);

  prep_weights<<<1024, 256, 0, stream>>>(W0, W1, W2, w0h, w0l, w1h, w1l, w2h, w2l);
  feat_kernel<<<1536, 1024, 0, stream>>>(points, normals, fvec, parts, rays, ro, Xh, Xl);
  fused_mlp<<<256, 512, 163840, stream>>>(Xh, Xl, w0h, w0l, w1h, w1l, w2h, w2l,
                                          b0, b1, b2, W3, b3, out);
}